// Round 8
// baseline (206.620 us; speedup 1.0000x reference)
//
#include <hip/hip_runtime.h>

// Laplacian-kernel regression, fused, bf16 MFMA 32x32x16.
//   d2 = ||x||^2 + ||z||^2 - 2 X.Z^T ; P = exp(-sqrt(d2)/10) ; out = P @ W
// R19: v18 (125.5us record) + stall-removal, same skeleton:
//  * raw s_barrier + counted waitcnts (HK idiom): __syncthreads forced
//    vmcnt(0) drains at every barrier, killing stream overlap. Now only
//    vmcnt(8) at kw16 (restage oldest) and lgkmcnt(0) where ds_writes
//    must be cross-wave visible.
//  * unified depth-4 stream sb[4][2]: Z(kw0..27) -> W-A(kw28..31) ->
//    W-A/W-B(PV-A) -> W-B/next-Z(PV-B). Every L2 load has >=4-step lead
//    across ALL phase boundaries; -32 arch VGPRs vs separate zb/wb.
//  * transform split by z-col half: j=0 before B2a; PV pass A (zw set
//    {0,1,4,5,8,9,12,13} = cols written by j=0) runs with j=1 transform
//    interleaved per-iteration (disjoint LDS bytes); B2b; PV pass B.
//    Transcendental VALU (~2k cyc) hides under PV-A MFMA.
// LDS 66,560B (2 blk/CU), grid 512 XCD-pinned, R1 persistent / R2
// time-share, MFMA order per-accumulator unchanged -> absmax ~same.
// Lessons kept: no >2 waves/SIMD (v13/v15 spill), no wave-tile shrink
// (v14 L2 doubling), no per-mt full-X restage (v16 FETCH blowup).

using frag8  = __attribute__((ext_vector_type(8)))  short;   // 8 bf16 (4 VGPRs)
using f32x16 = __attribute__((ext_vector_type(16))) float;   // 32x32 C/D frag

constexpr int Nn = 8192, Mm = 8192, Dd = 512, Yd = 256;
constexpr int BM = 64, BN = 256;
constexpr int MCH = 4, MPER = Mm / MCH, MT = MPER / BN;    // 2048, 8
constexpr int LDP = BN + 8;    // 264 ushort row stride for sP

// Fragment-tile layout (16-row groups, prep_v11):
// frag(g, c) = rows [16g,16g+16) x k [32c,32c+32), 512 ushorts at
// (g*KG + c)*512, element (r,k) at ushort lane16*8 + k%8 where
// lane16 = r%16 + 16*((k%32)/8).  Xf/Zf: KG=16 (K=512). Wf: rows=y, KG=256.
// 32x32x16 A/B-frag for lane L (r=L&31, h=L>>5) = one 16B chunk at
// base + kw*256 ushorts (kw = 16-k window), base = g0*8192 + lane_lo.

// workspace layout (bytes)
constexpr size_t OFF_XF  = 0;                               // 8 MB
constexpr size_t OFF_ZF  = OFF_XF + (size_t)Nn * Dd * 2;    // 8 MB
constexpr size_t OFF_WF  = OFF_ZF + (size_t)Mm * Dd * 2;    // 4 MB
constexpr size_t OFF_XSQ = OFF_WF + (size_t)Yd * Mm * 2;
constexpr size_t OFF_ZSQ = OFF_XSQ + (size_t)Nn * 4;
constexpr size_t WS_NEED = OFF_ZSQ + (size_t)Mm * 4;        // ~20.1 MB

__device__ __forceinline__ ushort f2bf(float f) {
    unsigned u = __builtin_bit_cast(unsigned, f);
    u += 0x7FFFu + ((u >> 16) & 1u);          // RNE (prep only)
    return (ushort)(u >> 16);
}

__device__ __forceinline__ void gload_lds16(const ushort* g, ushort* l) {
    __builtin_amdgcn_global_load_lds(
        (const __attribute__((address_space(1))) unsigned int*)(g),
        (__attribute__((address_space(3))) unsigned int*)(l), 16, 0, 0);
}

__device__ __forceinline__ void barr() {      // raw barrier, no forced drain
    __builtin_amdgcn_sched_barrier(0);
    __builtin_amdgcn_s_barrier();
    __builtin_amdgcn_sched_barrier(0);
}

// ---- prep (LDS-tiled, coalesced) — unchanged from v11 ----
__global__ __launch_bounds__(256) void prep_v11(
    const float* __restrict__ X, const float* __restrict__ Z,
    const float* __restrict__ W, ushort* __restrict__ Xf,
    ushort* __restrict__ Zf, ushort* __restrict__ Wf,
    float* __restrict__ xsq, float* __restrict__ zsq)
{
    __shared__ float tile[8320];                  // 16x517 (X/Z) or 32x260 (W)
    __shared__ float part[256];
    const int t = threadIdx.x, b = blockIdx.x;
    if (b < 1024) {
        const int g = (b < 512) ? b : b - 512;
        const float* src = (b < 512 ? X : Z) + (size_t)g * 16 * Dd;
        ushort* dst = (b < 512 ? Xf : Zf) + (size_t)g * 16 * 512;
        float* nrm = (b < 512 ? xsq : zsq) + g * 16;
        #pragma unroll
        for (int rep = 0; rep < 8; ++rep) {       // 2048 float4, coalesced
            const int idx = rep * 256 + t;
            const int r = idx >> 7, c4 = (idx & 127) * 4;
            const float4 v = *(const float4*)(src + (size_t)r * Dd + c4);
            float* d = tile + r * 517 + c4;
            d[0] = v.x; d[1] = v.y; d[2] = v.z; d[3] = v.w;
        }
        __syncthreads();
        {
            const int r = t & 15, s0 = (t >> 4) * 32;
            float sq = 0.0f;
            #pragma unroll
            for (int k = 0; k < 32; ++k) {
                const float v = tile[r * 517 + s0 + k];
                sq += v * v;
            }
            part[t] = sq;
        }
        __syncthreads();
        if (t < 16) {
            float sq = 0.0f;
            #pragma unroll
            for (int s = 0; s < 16; ++s) sq += part[t + 16 * s];
            nrm[t] = sq;
        }
        #pragma unroll
        for (int rep = 0; rep < 4; ++rep) {       // 1024 uint4 frag writes
            const int idx = rep * 256 + t;
            const int kg = idx >> 6, w = idx & 63;
            const int l16 = w & 15, quad = w >> 4;
            const float* s = tile + l16 * 517 + kg * 32 + quad * 8;
            uint4 pk;
            pk.x = (unsigned)f2bf(s[0]) | ((unsigned)f2bf(s[1]) << 16);
            pk.y = (unsigned)f2bf(s[2]) | ((unsigned)f2bf(s[3]) << 16);
            pk.z = (unsigned)f2bf(s[4]) | ((unsigned)f2bf(s[5]) << 16);
            pk.w = (unsigned)f2bf(s[6]) | ((unsigned)f2bf(s[7]) << 16);
            *(uint4*)(dst + (size_t)kg * 512 + w * 8) = pk;
        }
    } else {
        const int zg = b - 1024;                  // 32-z stripe of W
        const float* src = W + (size_t)zg * 32 * Yd;
        #pragma unroll
        for (int rep = 0; rep < 8; ++rep) {
            const int idx = rep * 256 + t;
            const int r = idx >> 6, c4 = (idx & 63) * 4;
            const float4 v = *(const float4*)(src + (size_t)r * Yd + c4);
            float* d = tile + r * 260 + c4;
            d[0] = v.x; d[1] = v.y; d[2] = v.z; d[3] = v.w;
        }
        __syncthreads();
        #pragma unroll
        for (int rep = 0; rep < 4; ++rep) {
            const int idx = rep * 256 + t;
            const int yg = idx >> 6, w = idx & 63;
            const int l16 = w & 15, quad = w >> 4;
            const int y = yg * 16 + l16;
            ushort rr[8];
            #pragma unroll
            for (int j = 0; j < 8; ++j)
                rr[j] = f2bf(tile[(quad * 8 + j) * 260 + y]);
            uint4 pk;
            pk.x = (unsigned)rr[0] | ((unsigned)rr[1] << 16);
            pk.y = (unsigned)rr[2] | ((unsigned)rr[3] << 16);
            pk.z = (unsigned)rr[4] | ((unsigned)rr[5] << 16);
            pk.w = (unsigned)rr[6] | ((unsigned)rr[7] << 16);
            *(uint4*)(Wf + ((size_t)yg * 256 + zg) * 512 + w * 8) = pk;
        }
    }
}

// ---- main fused kernel (v19) ----
__global__ __launch_bounds__(256, 2) void laplace_v19(
    const ushort* __restrict__ Xf, const ushort* __restrict__ Zf,
    const ushort* __restrict__ Wf, const float* __restrict__ xsqg,
    const float* __restrict__ zsqg, float* __restrict__ O)
{
    __shared__ ushort sM[16384 + 16896];          // 66,560 B total
    ushort* R1 = sM;                              // X k[0,256): 32 units * 512
    ushort* R2 = sM + 16384;                      // X k[256,512) UNION sP[64][LDP]

    const int t = threadIdx.x, wid = t >> 6, lane = t & 63;
    const int l32 = lane & 31, hb = lane >> 5;

    // PV z-window order: set A = cols written by transform j=0
    constexpr int ZWA[8] = {0, 1, 4, 5, 8, 9, 12, 13};
    constexpr int ZWB[8] = {2, 3, 6, 7, 10, 11, 14, 15};

    // XCD-aware swizzle: z-chunk pinned to an XCD pair (grid = 512, 1-D)
    const int bid = blockIdx.x;
    const int xcd = bid & 7;
    const int chunk = xcd >> 1;                   // 0..3
    const int xi = ((xcd & 1) << 6) + (bid >> 3); // 0..127
    const int row0 = xi * BM;
    const int zbase = chunk * MPER;

    const unsigned lane_lo = (unsigned)(((l32 & 15) + 16 * hb) * 8);
    const unsigned xsrc_base =
        (unsigned)(((row0 >> 4) + (l32 >> 4)) * 8192) + lane_lo;

    // ---- prologue: stage R1 (kw 0..15) and R2 (kw 16..31) once ----
    #pragma unroll
    for (int q = 0; q < 8; ++q) {
        const int f = wid * 8 + q;                // 0..31
        const int kw = f >> 1, i = f & 1;
        const ushort* s1 = Xf + xsrc_base + (unsigned)i * 16384u
                              + (unsigned)kw * 256u;
        gload_lds16(s1,            R1 + f * 512);
        gload_lds16(s1 + 4096u,    R2 + f * 512);   // +16 k-windows
    }

    f32x16 Oa[2][2];
    #pragma unroll
    for (int i = 0; i < 2; ++i)
        #pragma unroll
        for (int j = 0; j < 2; ++j)
            #pragma unroll
            for (int r = 0; r < 16; ++r) Oa[i][j][r] = 0.0f;

    // unified depth-4 L2 stream (Z in QK, W in PV, next-Z in PV-B tail)
    unsigned zo0 = ((unsigned)((zbase >> 4) + wid * 4 + (l32 >> 4))) * 8192u
                   + lane_lo;
    unsigned zo1 = zo0 + 16384u;                  // +2 z 16-row groups (j=1)
    frag8 sb[4][2];
    #pragma unroll
    for (int p = 0; p < 4; ++p) {
        sb[p][0] = *(const frag8*)(Zf + zo0 + (unsigned)p * 256u);
        sb[p][1] = *(const frag8*)(Zf + zo1 + (unsigned)p * 256u);
    }

    asm volatile("s_waitcnt vmcnt(0)" ::: "memory");
    barr();                                       // staging + sb complete

    unsigned zwg = (unsigned)(zbase >> 4);        // W z 16-group base
    const unsigned wyg = (unsigned)(wid * 4 + (l32 >> 4));
    const int pa0 = l32 * LDP + 8 * hb;

    #pragma unroll 1
    for (int mt = 0; mt < MT; ++mt) {
        const int zc0 = zbase + mt * 256 + wid * 64 + l32;
        const float zs0 = zsqg[zc0];
        const float zs1 = zsqg[zc0 + 32];
        const unsigned wo0 = wyg * 131072u + zwg * 256u + lane_lo;

        f32x16 S[2][2];
        #pragma unroll
        for (int i = 0; i < 2; ++i)
            #pragma unroll
            for (int j = 0; j < 2; ++j)
                #pragma unroll
                for (int r = 0; r < 16; ++r) S[i][j][r] = 0.0f;

        // xa depth-2 from R1
        frag8 xa[2][2];
        #pragma unroll
        for (int p = 0; p < 2; ++p)
            #pragma unroll
            for (int i = 0; i < 2; ++i)
                xa[p][i] = *(const frag8*)(R1 + (2 * p + i) * 512 + lane * 8);

        // ---- QK: merged kw 0..31; h0 from R1, h1 from R2 ----
        #pragma unroll
        for (int kw = 0; kw < 32; ++kw) {
            if (kw == 16) {
                // R2 restage (8 oldest gloads) done; newest sb stay in flight
                asm volatile("s_waitcnt vmcnt(8)" ::: "memory");
                barr();
                #pragma unroll
                for (int p = 0; p < 2; ++p)
                    #pragma unroll
                    for (int i = 0; i < 2; ++i)
                        xa[p][i] = *(const frag8*)(
                            R2 + (2 * p + i) * 512 + lane * 8);
            }
            const int s = kw & 1, zs = kw & 3;
            __builtin_amdgcn_s_setprio(1);
            S[0][0] = __builtin_amdgcn_mfma_f32_32x32x16_bf16(
                xa[s][0], sb[zs][0], S[0][0], 0, 0, 0);
            S[0][1] = __builtin_amdgcn_mfma_f32_32x32x16_bf16(
                xa[s][0], sb[zs][1], S[0][1], 0, 0, 0);
            S[1][0] = __builtin_amdgcn_mfma_f32_32x32x16_bf16(
                xa[s][1], sb[zs][0], S[1][0], 0, 0, 0);
            S[1][1] = __builtin_amdgcn_mfma_f32_32x32x16_bf16(
                xa[s][1], sb[zs][1], S[1][1], 0, 0, 0);
            __builtin_amdgcn_s_setprio(0);
            // xa refill (depth-2)
            if (kw + 2 < 16) {
                #pragma unroll
                for (int i = 0; i < 2; ++i)
                    xa[s][i] = *(const frag8*)(
                        R1 + (2 * (kw + 2) + i) * 512 + lane * 8);
            } else if (kw >= 16 && kw + 2 < 32) {
                #pragma unroll
                for (int i = 0; i < 2; ++i)
                    xa[s][i] = *(const frag8*)(
                        R2 + (2 * (kw + 2 - 16) + i) * 512 + lane * 8);
            }
            // sb refill: Z until kw27, then PV-A's W frags (ZWA[0..3])
            if (kw + 4 < 32) {
                sb[zs][0] = *(const frag8*)(Zf + zo0
                                            + (unsigned)(kw + 4) * 256u);
                sb[zs][1] = *(const frag8*)(Zf + zo1
                                            + (unsigned)(kw + 4) * 256u);
            } else {
                const unsigned za = (unsigned)ZWA[kw - 28];
                sb[zs][0] = *(const frag8*)(Wf + wo0 + za * 256u);
                sb[zs][1] = *(const frag8*)(Wf + wo0 + 262144u + za * 256u);
            }
        }
        zo0 += 131072u; zo1 += 131072u;           // advance Z stream for next mt

        barr();   // B1: all waves done reading R2 (X h1); no drain needed

        // ---- transform j=0 -> sP cols C0 (wid*64 + l32) ----
        {
            const int col = wid * 64 + l32;
            #pragma unroll
            for (int i = 0; i < 2; ++i) {
                #pragma unroll
                for (int g = 0; g < 4; ++g) {
                    const float4 xq = *(const float4*)(
                        xsqg + row0 + 32 * i + 8 * g + 4 * hb);
                    const float xr4[4] = {xq.x, xq.y, xq.z, xq.w};
                    #pragma unroll
                    for (int rr = 0; rr < 4; ++rr) {
                        const float sv = S[i][0][4 * g + rr];
                        float d2 = fmaf(sv, -2.0f, xr4[rr] + zs0);
                        d2 = fmaxf(d2, 1e-20f);
                        const float dist = d2 * __frsqrt_rn(d2);     // sqrt
                        const float e = __builtin_amdgcn_exp2f(
                            dist * -0.14426950408889634f);   // exp(-d/10)
                        R2[(32 * i + rr + 8 * g + 4 * hb) * LDP + col] =
                            (ushort)(__builtin_bit_cast(unsigned, e) >> 16);
                    }
                }
            }
        }
        asm volatile("s_waitcnt lgkmcnt(0)" ::: "memory");
        barr();   // B2a: sP cols C0 visible

        // ---- PV pass A (zw in ZWA) fused with transform j=1 ----
        frag8 pa[2][2];
        #pragma unroll
        for (int p = 0; p < 2; ++p)
            #pragma unroll
            for (int i = 0; i < 2; ++i)
                pa[p][i] = *(const frag8*)(R2 + pa0 + i * 32 * LDP
                                           + ZWA[p] * 16);
        #pragma unroll
        for (int p = 0; p < 8; ++p) {
            const int s2 = p & 1, ss = p & 3;
            __builtin_amdgcn_s_setprio(1);
            Oa[0][0] = __builtin_amdgcn_mfma_f32_32x32x16_bf16(
                pa[s2][0], sb[ss][0], Oa[0][0], 0, 0, 0);
            Oa[0][1] = __builtin_amdgcn_mfma_f32_32x32x16_bf16(
                pa[s2][0], sb[ss][1], Oa[0][1], 0, 0, 0);
            Oa[1][0] = __builtin_amdgcn_mfma_f32_32x32x16_bf16(
                pa[s2][1], sb[ss][0], Oa[1][0], 0, 0, 0);
            Oa[1][1] = __builtin_amdgcn_mfma_f32_32x32x16_bf16(
                pa[s2][1], sb[ss][1], Oa[1][1], 0, 0, 0);
            __builtin_amdgcn_s_setprio(0);
            if (p + 2 < 8) {
                #pragma unroll
                for (int i = 0; i < 2; ++i)
                    pa[s2][i] = *(const frag8*)(R2 + pa0 + i * 32 * LDP
                                                + ZWA[p + 2] * 16);
            }
            // sb refill: rest of W-A, then W-B head
            if (p + 4 < 8) {
                const unsigned za = (unsigned)ZWA[p + 4];
                sb[ss][0] = *(const frag8*)(Wf + wo0 + za * 256u);
                sb[ss][1] = *(const frag8*)(Wf + wo0 + 262144u + za * 256u);
            } else {
                const unsigned zb2 = (unsigned)ZWB[p - 4];
                sb[ss][0] = *(const frag8*)(Wf + wo0 + zb2 * 256u);
                sb[ss][1] = *(const frag8*)(Wf + wo0 + 262144u + zb2 * 256u);
            }
            // transform j=1 chunk (i = p>>2, g = p&3) -> sP cols C1
            {
                const int ci = p >> 2, cg = p & 3;
                const float4 xq = *(const float4*)(
                    xsqg + row0 + 32 * ci + 8 * cg + 4 * hb);
                const float xr4[4] = {xq.x, xq.y, xq.z, xq.w};
                const int col = wid * 64 + 32 + l32;
                #pragma unroll
                for (int rr = 0; rr < 4; ++rr) {
                    const float sv = S[ci][1][4 * cg + rr];
                    float d2 = fmaf(sv, -2.0f, xr4[rr] + zs1);
                    d2 = fmaxf(d2, 1e-20f);
                    const float dist = d2 * __frsqrt_rn(d2);     // sqrt
                    const float e = __builtin_amdgcn_exp2f(
                        dist * -0.14426950408889634f);           // exp(-d/10)
                    R2[(32 * ci + rr + 8 * cg + 4 * hb) * LDP + col] =
                        (ushort)(__builtin_bit_cast(unsigned, e) >> 16);
                }
            }
        }
        asm volatile("s_waitcnt lgkmcnt(0)" ::: "memory");
        barr();   // B2b: sP cols C1 visible

        // ---- PV pass B (zw in ZWB); tail slots prefetch next-mt Z ----
        #pragma unroll
        for (int p = 0; p < 2; ++p)
            #pragma unroll
            for (int i = 0; i < 2; ++i)
                pa[p][i] = *(const frag8*)(R2 + pa0 + i * 32 * LDP
                                           + ZWB[p] * 16);
        #pragma unroll
        for (int q = 0; q < 8; ++q) {
            const int s2 = q & 1, ss = q & 3;
            __builtin_amdgcn_s_setprio(1);
            Oa[0][0] = __builtin_amdgcn_mfma_f32_32x32x16_bf16(
                pa[s2][0], sb[ss][0], Oa[0][0], 0, 0, 0);
            Oa[0][1] = __builtin_amdgcn_mfma_f32_32x32x16_bf16(
                pa[s2][0], sb[ss][1], Oa[0][1], 0, 0, 0);
            Oa[1][0] = __builtin_amdgcn_mfma_f32_32x32x16_bf16(
                pa[s2][1], sb[ss][0], Oa[1][0], 0, 0, 0);
            Oa[1][1] = __builtin_amdgcn_mfma_f32_32x32x16_bf16(
                pa[s2][1], sb[ss][1], Oa[1][1], 0, 0, 0);
            __builtin_amdgcn_s_setprio(0);
            if (q + 2 < 8) {
                #pragma unroll
                for (int i = 0; i < 2; ++i)
                    pa[s2][i] = *(const frag8*)(R2 + pa0 + i * 32 * LDP
                                                + ZWB[q + 2] * 16);
            }
            if (q + 4 < 8) {
                const unsigned zb2 = (unsigned)ZWB[q + 4];
                sb[ss][0] = *(const frag8*)(Wf + wo0 + zb2 * 256u);
                sb[ss][1] = *(const frag8*)(Wf + wo0 + 262144u + zb2 * 256u);
            } else if (mt + 1 < MT) {             // next-mt Z kw (q-4)
                sb[ss][0] = *(const frag8*)(Zf + zo0
                                            + (unsigned)(q - 4) * 256u);
                sb[ss][1] = *(const frag8*)(Zf + zo1
                                            + (unsigned)(q - 4) * 256u);
            }
        }
        barr();   // B3: sP reads done, R2 free

        // ---- tail: restage X h1 into R2 (8 gloads = oldest for kw16) ----
        if (mt + 1 < MT) {
            #pragma unroll
            for (int q = 0; q < 8; ++q) {
                const int f = wid * 8 + q;        // 0..31
                const int kw = (f >> 1) + 16, i = f & 1;
                gload_lds16(Xf + xsrc_base + (unsigned)i * 16384u
                               + (unsigned)kw * 256u,
                            R2 + f * 512);
            }
            __builtin_amdgcn_sched_barrier(0);
        }
        zwg += 16u;
    }

    // ---- epilogue: combine MCH=4 chunks via fp32 atomics (XCD-local) ----
    #pragma unroll
    for (int i = 0; i < 2; ++i)
        #pragma unroll
        for (int jy = 0; jy < 2; ++jy) {
            const int yg = wid * 64 + 32 * jy + l32;
            #pragma unroll
            for (int r = 0; r < 16; ++r) {
                const int xg = row0 + 32 * i + (r & 3) + 8 * (r >> 2) + 4 * hb;
                atomicAdd(&O[(size_t)xg * Yd + yg], Oa[i][jy][r]);
            }
        }
}

// ---- fallback (fp32 VALU fused kernel) if workspace is too small ----
constexpr int FBM = 64, FBN = 64, FBK = 64;
constexpr int FMCH = 4, FMCHUNK = Mm / FMCH, FMSTEPS = FMCHUNK / FBN, FDSTEPS = Dd / FBK;
constexpr int FLDA = FBK + 1, FLDSS = FBN + 1;

__global__ __launch_bounds__(256, 3) void laplace_fused_v1(
    const float* __restrict__ X, const float* __restrict__ Z,
    const float* __restrict__ W, float* __restrict__ O)
{
    __shared__ float sX[FBM * FLDA];
    __shared__ float sZ[FBN * FLDA];
    __shared__ float sS[FBM * FLDSS];
    const int t = threadIdx.x, pr = t >> 4, pc = t & 15, sc4 = pc * 4;
    const int row0 = blockIdx.x * FBM, mbase = blockIdx.y * FMCHUNK;
    float o[4][4][4];
    #pragma unroll
    for (int i = 0; i < 4; ++i)
        for (int yb = 0; yb < 4; ++yb)
            for (int j = 0; j < 4; ++j) o[i][yb][j] = 0.0f;
    for (int ms = 0; ms < FMSTEPS; ++ms) {
        const int zrow0 = mbase + ms * FBN;
        float s[4][4];
        #pragma unroll
        for (int i = 0; i < 4; ++i)
            for (int j = 0; j < 4; ++j) s[i][j] = 0.0f;
        for (int kk = 0; kk < FDSTEPS; ++kk) {
            const int k0 = kk * FBK;
            __syncthreads();
            #pragma unroll
            for (int rep = 0; rep < 4; ++rep) {
                const int r = pr + rep * 16;
                const float4 xv = *reinterpret_cast<const float4*>(X + (size_t)(row0 + r) * Dd + k0 + sc4);
                const float4 zv = *reinterpret_cast<const float4*>(Z + (size_t)(zrow0 + r) * Dd + k0 + sc4);
                float* dx = sX + r * FLDA + sc4;
                dx[0] = xv.x; dx[1] = xv.y; dx[2] = xv.z; dx[3] = xv.w;
                float* dz = sZ + r * FLDA + sc4;
                dz[0] = zv.x; dz[1] = zv.y; dz[2] = zv.z; dz[3] = zv.w;
            }
            __syncthreads();
            #pragma unroll 4
            for (int k = 0; k < FBK; ++k) {
                float xr[4], zc[4];
                #pragma unroll
                for (int i = 0; i < 4; ++i) xr[i] = sX[(pr * 4 + i) * FLDA + k];
                #pragma unroll
                for (int j = 0; j < 4; ++j) zc[j] = sZ[(pc * 4 + j) * FLDA + k];
                #pragma unroll
                for (int i = 0; i < 4; ++i)
                    #pragma unroll
                    for (int j = 0; j < 4; ++j) {
                        const float d = xr[i] - zc[j];
                        s[i][j] = fmaf(d, d, s[i][j]);
                    }
            }
        }
        #pragma unroll
        for (int i = 0; i < 4; ++i)
            for (int j = 0; j < 4; ++j)
                sS[(pr * 4 + i) * FLDSS + sc4 + j] = __expf(-sqrtf(s[i][j]) * 0.1f);
        __syncthreads();
        #pragma unroll 2
        for (int c = 0; c < FBN; ++c) {
            float sv[4];
            #pragma unroll
            for (int i = 0; i < 4; ++i) sv[i] = sS[(pr * 4 + i) * FLDSS + c];
            const float* wrow = W + (size_t)(zrow0 + c) * Yd;
            #pragma unroll
            for (int yb = 0; yb < 4; ++yb) {
                const float4 wv = *reinterpret_cast<const float4*>(wrow + yb * 64 + sc4);
                #pragma unroll
                for (int i = 0; i < 4; ++i) {
                    o[i][yb][0] = fmaf(sv[i], wv.x, o[i][yb][0]);
                    o[i][yb][1] = fmaf(sv[i], wv.y, o[i][yb][1]);
                    o[i][yb][2] = fmaf(sv[i], wv.z, o[i][yb][2]);
                    o[i][yb][3] = fmaf(sv[i], wv.w, o[i][yb][3]);
                }
            }
        }
        __syncthreads();
    }
    #pragma unroll
    for (int i = 0; i < 4; ++i) {
        const size_t rbase = (size_t)(row0 + pr * 4 + i) * Yd;
        #pragma unroll
        for (int yb = 0; yb < 4; ++yb)
            for (int j = 0; j < 4; ++j)
                atomicAdd(O + rbase + yb * 64 + sc4 + j, o[i][yb][j]);
    }
}

extern "C" void kernel_launch(void* const* d_in, const int* in_sizes, int n_in,
                              void* d_out, int out_size, void* d_ws, size_t ws_size,
                              hipStream_t stream) {
    const float* X = (const float*)d_in[0];   // batch   [8192, 512]
    const float* Z = (const float*)d_in[1];   // centers [8192, 512]
    const float* W = (const float*)d_in[2];   // weight  [8192, 256]
    float* O = (float*)d_out;                 // pred    [8192, 256]

    hipMemsetAsync(d_out, 0, (size_t)out_size * sizeof(float), stream);

    if (ws_size < WS_NEED) {
        dim3 grid(Nn / FBM, FMCH);
        laplace_fused_v1<<<grid, dim3(256), 0, stream>>>(X, Z, W, O);
        return;
    }

    char* ws = (char*)d_ws;
    ushort* Xf  = (ushort*)(ws + OFF_XF);
    ushort* Zf  = (ushort*)(ws + OFF_ZF);
    ushort* Wf  = (ushort*)(ws + OFF_WF);
    float*  xsq = (float*)(ws + OFF_XSQ);
    float*  zsq = (float*)(ws + OFF_ZSQ);

    prep_v11<<<dim3(1024 + 256), dim3(256), 0, stream>>>(
        X, Z, W, Xf, Zf, Wf, xsq, zsq);

    laplace_v19<<<dim3(512), dim3(256), 0, stream>>>(
        Xf, Zf, Wf, xsq, zsq, O);
}

// Round 9
// 203.953 us; speedup vs baseline: 1.0131x; 1.0131x over previous
//
#include <hip/hip_runtime.h>

// Laplacian-kernel regression, fused, bf16 MFMA 32x32x16.
//   d2 = ||x||^2 + ||z||^2 - 2 X.Z^T ; P = exp(-sqrt(d2)/10) ; out = P @ W
// R20: v18 (125.5us record) bit-identical + ONE change: anti-phase stagger
// of co-resident blocks. Diagnosis: per-SIMD per-mt wall 37.6k cyc =
// 12.4k MFMA + 7.5k VALU + ~17k BOTH-waves-stalled; the 2 blocks/CU run
// identical phase structure and can lock in-phase (transform VALU bursts
// and barrier drains collide). Blocks with (bid>>8)&1 (presumed partner
// set: bid and bid+256 share a CU, same XCD/chunk) sleep ~16k cyc once at
// entry (after staging issue) -> steady-state QK(A) || transform+PV(B).
// Cost if theory wrong: <=3.4us one-time on half the blocks.
// v19 lesson: barrier drains are NOT the bottleneck (removing them lost
// 5%); v18's win was depth-4 prefetch + merged kw loop + wb-under-
// transform. Register ceiling exact (128 arch + 128 acc): no +reg changes.

using frag8  = __attribute__((ext_vector_type(8)))  short;   // 8 bf16 (4 VGPRs)
using f32x16 = __attribute__((ext_vector_type(16))) float;   // 32x32 C/D frag

constexpr int Nn = 8192, Mm = 8192, Dd = 512, Yd = 256;
constexpr int BM = 64, BN = 256;
constexpr int MCH = 4, MPER = Mm / MCH, MT = MPER / BN;    // 2048, 8
constexpr int LDP = BN + 8;    // 264 ushort row stride for sP

// Fragment-tile layout (16-row groups, prep_v11):
// frag(g, c) = rows [16g,16g+16) x k [32c,32c+32), 512 ushorts at
// (g*KG + c)*512, element (r,k) at ushort lane16*8 + k%8 where
// lane16 = r%16 + 16*((k%32)/8).  Xf/Zf: KG=16 (K=512). Wf: rows=y, KG=256.
// 32x32x16 A/B-frag for lane L (r=L&31, h=L>>5) = one 16B chunk at
// base + kw*256 ushorts (kw = 16-k window), base = g0*8192 + lane_lo.

// workspace layout (bytes)
constexpr size_t OFF_XF  = 0;                               // 8 MB
constexpr size_t OFF_ZF  = OFF_XF + (size_t)Nn * Dd * 2;    // 8 MB
constexpr size_t OFF_WF  = OFF_ZF + (size_t)Mm * Dd * 2;    // 4 MB
constexpr size_t OFF_XSQ = OFF_WF + (size_t)Yd * Mm * 2;
constexpr size_t OFF_ZSQ = OFF_XSQ + (size_t)Nn * 4;
constexpr size_t WS_NEED = OFF_ZSQ + (size_t)Mm * 4;        // ~20.1 MB

__device__ __forceinline__ ushort f2bf(float f) {
    unsigned u = __builtin_bit_cast(unsigned, f);
    u += 0x7FFFu + ((u >> 16) & 1u);          // RNE (prep only)
    return (ushort)(u >> 16);
}

__device__ __forceinline__ void gload_lds16(const ushort* g, ushort* l) {
    __builtin_amdgcn_global_load_lds(
        (const __attribute__((address_space(1))) unsigned int*)(g),
        (__attribute__((address_space(3))) unsigned int*)(l), 16, 0, 0);
}

// ---- prep (LDS-tiled, coalesced) — unchanged from v11 ----
__global__ __launch_bounds__(256) void prep_v11(
    const float* __restrict__ X, const float* __restrict__ Z,
    const float* __restrict__ W, ushort* __restrict__ Xf,
    ushort* __restrict__ Zf, ushort* __restrict__ Wf,
    float* __restrict__ xsq, float* __restrict__ zsq)
{
    __shared__ float tile[8320];                  // 16x517 (X/Z) or 32x260 (W)
    __shared__ float part[256];
    const int t = threadIdx.x, b = blockIdx.x;
    if (b < 1024) {
        const int g = (b < 512) ? b : b - 512;
        const float* src = (b < 512 ? X : Z) + (size_t)g * 16 * Dd;
        ushort* dst = (b < 512 ? Xf : Zf) + (size_t)g * 16 * 512;
        float* nrm = (b < 512 ? xsq : zsq) + g * 16;
        #pragma unroll
        for (int rep = 0; rep < 8; ++rep) {       // 2048 float4, coalesced
            const int idx = rep * 256 + t;
            const int r = idx >> 7, c4 = (idx & 127) * 4;
            const float4 v = *(const float4*)(src + (size_t)r * Dd + c4);
            float* d = tile + r * 517 + c4;
            d[0] = v.x; d[1] = v.y; d[2] = v.z; d[3] = v.w;
        }
        __syncthreads();
        {
            const int r = t & 15, s0 = (t >> 4) * 32;
            float sq = 0.0f;
            #pragma unroll
            for (int k = 0; k < 32; ++k) {
                const float v = tile[r * 517 + s0 + k];
                sq += v * v;
            }
            part[t] = sq;
        }
        __syncthreads();
        if (t < 16) {
            float sq = 0.0f;
            #pragma unroll
            for (int s = 0; s < 16; ++s) sq += part[t + 16 * s];
            nrm[t] = sq;
        }
        #pragma unroll
        for (int rep = 0; rep < 4; ++rep) {       // 1024 uint4 frag writes
            const int idx = rep * 256 + t;
            const int kg = idx >> 6, w = idx & 63;
            const int l16 = w & 15, quad = w >> 4;
            const float* s = tile + l16 * 517 + kg * 32 + quad * 8;
            uint4 pk;
            pk.x = (unsigned)f2bf(s[0]) | ((unsigned)f2bf(s[1]) << 16);
            pk.y = (unsigned)f2bf(s[2]) | ((unsigned)f2bf(s[3]) << 16);
            pk.z = (unsigned)f2bf(s[4]) | ((unsigned)f2bf(s[5]) << 16);
            pk.w = (unsigned)f2bf(s[6]) | ((unsigned)f2bf(s[7]) << 16);
            *(uint4*)(dst + (size_t)kg * 512 + w * 8) = pk;
        }
    } else {
        const int zg = b - 1024;                  // 32-z stripe of W
        const float* src = W + (size_t)zg * 32 * Yd;
        #pragma unroll
        for (int rep = 0; rep < 8; ++rep) {
            const int idx = rep * 256 + t;
            const int r = idx >> 6, c4 = (idx & 63) * 4;
            const float4 v = *(const float4*)(src + (size_t)r * Yd + c4);
            float* d = tile + r * 260 + c4;
            d[0] = v.x; d[1] = v.y; d[2] = v.z; d[3] = v.w;
        }
        __syncthreads();
        #pragma unroll
        for (int rep = 0; rep < 4; ++rep) {
            const int idx = rep * 256 + t;
            const int yg = idx >> 6, w = idx & 63;
            const int l16 = w & 15, quad = w >> 4;
            const int y = yg * 16 + l16;
            ushort rr[8];
            #pragma unroll
            for (int j = 0; j < 8; ++j)
                rr[j] = f2bf(tile[(quad * 8 + j) * 260 + y]);
            uint4 pk;
            pk.x = (unsigned)rr[0] | ((unsigned)rr[1] << 16);
            pk.y = (unsigned)rr[2] | ((unsigned)rr[3] << 16);
            pk.z = (unsigned)rr[4] | ((unsigned)rr[5] << 16);
            pk.w = (unsigned)rr[6] | ((unsigned)rr[7] << 16);
            *(uint4*)(Wf + ((size_t)yg * 256 + zg) * 512 + w * 8) = pk;
        }
    }
}

// ---- main fused kernel (v20): v18 + co-resident block stagger ----
__global__ __launch_bounds__(256, 2) void laplace_v20(
    const ushort* __restrict__ Xf, const ushort* __restrict__ Zf,
    const ushort* __restrict__ Wf, const float* __restrict__ xsqg,
    const float* __restrict__ zsqg, float* __restrict__ O)
{
    __shared__ ushort sM[16384 + 16896];          // 66,560 B total
    ushort* R1 = sM;                              // X k[0,256): 32 units * 512
    ushort* R2 = sM + 16384;                      // X k[256,512) UNION sP[64][LDP]

    const int t = threadIdx.x, wid = t >> 6, lane = t & 63;
    const int l32 = lane & 31, hb = lane >> 5;

    // XCD-aware swizzle: z-chunk pinned to an XCD pair (grid = 512, 1-D)
    const int bid = blockIdx.x;
    const int xcd = bid & 7;
    const int chunk = xcd >> 1;                   // 0..3
    const int xi = ((xcd & 1) << 6) + (bid >> 3); // 0..127
    const int row0 = xi * BM;
    const int zbase = chunk * MPER;

    const unsigned lane_lo = (unsigned)(((l32 & 15) + 16 * hb) * 8);
    const unsigned xsrc_base =
        (unsigned)(((row0 >> 4) + (l32 >> 4)) * 8192) + lane_lo;

    // ---- prologue: stage R1 (kw 0..15) and R2 (kw 16..31) once ----
    #pragma unroll
    for (int q = 0; q < 8; ++q) {
        const int f = wid * 8 + q;                // 0..31
        const int kw = f >> 1, i = f & 1;
        const ushort* s1 = Xf + xsrc_base + (unsigned)i * 16384u
                              + (unsigned)kw * 256u;
        gload_lds16(s1,            R1 + f * 512);
        gload_lds16(s1 + 4096u,    R2 + f * 512);   // +16 k-windows
    }

    f32x16 Oa[2][2];
    #pragma unroll
    for (int i = 0; i < 2; ++i)
        #pragma unroll
        for (int j = 0; j < 2; ++j)
            #pragma unroll
            for (int r = 0; r < 16; ++r) Oa[i][j][r] = 0.0f;

    // Z stream state; zb depth-4 rolling
    unsigned zo0 = ((unsigned)((zbase >> 4) + wid * 4 + (l32 >> 4))) * 8192u
                   + lane_lo;
    unsigned zo1 = zo0 + 16384u;                  // +2 z 16-row groups (j=1)
    frag8 zb[4][2];
    #pragma unroll
    for (int p = 0; p < 4; ++p) {
        zb[p][0] = *(const frag8*)(Zf + zo0 + (unsigned)p * 256u);
        zb[p][1] = *(const frag8*)(Zf + zo1 + (unsigned)p * 256u);
    }

    // ---- anti-phase stagger: presumed co-resident partner set sleeps
    //      ~16k cyc (~half a QK phase) while its staging loads fly ----
    if ((bid >> 8) & 1) {
        __builtin_amdgcn_s_sleep(127);            // ~8k cyc
        __builtin_amdgcn_s_sleep(127);            // ~8k cyc
    }

    asm volatile("s_waitcnt vmcnt(0)" ::: "memory");
    __syncthreads();                              // staging + zb complete

    unsigned zwg = (unsigned)(zbase >> 4);        // W z 16-group base
    const unsigned wyg = (unsigned)(wid * 4 + (l32 >> 4));
    const int pa0 = l32 * LDP + 8 * hb;

    #pragma unroll 1
    for (int mt = 0; mt < MT; ++mt) {
        const int zc0 = zbase + mt * 256 + wid * 64 + l32;
        const float zs0 = zsqg[zc0];
        const float zs1 = zsqg[zc0 + 32];

        f32x16 S[2][2];
        #pragma unroll
        for (int i = 0; i < 2; ++i)
            #pragma unroll
            for (int j = 0; j < 2; ++j)
                #pragma unroll
                for (int r = 0; r < 16; ++r) S[i][j][r] = 0.0f;

        // xa depth-2 from R1
        frag8 xa[2][2];
        #pragma unroll
        for (int p = 0; p < 2; ++p)
            #pragma unroll
            for (int i = 0; i < 2; ++i)
                xa[p][i] = *(const frag8*)(R1 + (2 * p + i) * 512 + lane * 8);

        // ---- QK: merged kw 0..31; h0 from R1, h1 from R2 ----
        #pragma unroll
        for (int kw = 0; kw < 32; ++kw) {
            if (kw == 16) {
                // R2 restage (8 oldest gloads) done; keep newest zb in flight
                asm volatile("s_waitcnt vmcnt(8)" ::: "memory");
                __syncthreads();
                #pragma unroll
                for (int p = 0; p < 2; ++p)
                    #pragma unroll
                    for (int i = 0; i < 2; ++i)
                        xa[p][i] = *(const frag8*)(
                            R2 + (2 * p + i) * 512 + lane * 8);
            }
            const int s = kw & 1, zs = kw & 3;
            __builtin_amdgcn_s_setprio(1);
            S[0][0] = __builtin_amdgcn_mfma_f32_32x32x16_bf16(
                xa[s][0], zb[zs][0], S[0][0], 0, 0, 0);
            S[0][1] = __builtin_amdgcn_mfma_f32_32x32x16_bf16(
                xa[s][0], zb[zs][1], S[0][1], 0, 0, 0);
            S[1][0] = __builtin_amdgcn_mfma_f32_32x32x16_bf16(
                xa[s][1], zb[zs][0], S[1][0], 0, 0, 0);
            S[1][1] = __builtin_amdgcn_mfma_f32_32x32x16_bf16(
                xa[s][1], zb[zs][1], S[1][1], 0, 0, 0);
            __builtin_amdgcn_s_setprio(0);
            // xa refill (depth-2); skip the pre-barrier boundary (re-init at 16)
            if (kw + 2 < 16) {
                #pragma unroll
                for (int i = 0; i < 2; ++i)
                    xa[s][i] = *(const frag8*)(
                        R1 + (2 * (kw + 2) + i) * 512 + lane * 8);
            } else if (kw >= 16 && kw + 2 < 32) {
                #pragma unroll
                for (int i = 0; i < 2; ++i)
                    xa[s][i] = *(const frag8*)(
                        R2 + (2 * (kw + 2 - 16) + i) * 512 + lane * 8);
            }
            // zb refill (depth-4) — crosses the kw16 barrier seamlessly
            if (kw + 4 < 32) {
                zb[zs][0] = *(const frag8*)(Zf + zo0
                                            + (unsigned)(kw + 4) * 256u);
                zb[zs][1] = *(const frag8*)(Zf + zo1
                                            + (unsigned)(kw + 4) * 256u);
            }
        }

        __syncthreads();   // B1: all waves done reading R2 (X h1)

        // ---- wb depth-4 preload (reuses zb's dead regs); lands under
        //      transform's ~1500cyc of VALU ----
        const unsigned wo0 = wyg * 131072u + zwg * 256u + lane_lo;
        frag8 wb[4][2];
        #pragma unroll
        for (int p = 0; p < 4; ++p) {
            wb[p][0] = *(const frag8*)(Wf + wo0 + (unsigned)p * 256u);
            wb[p][1] = *(const frag8*)(Wf + wo0 + 262144u
                                       + (unsigned)p * 256u);
        }

        // ---- transform S -> sP in R2 (C/D: col=l32, row=(r&3)+8*(r>>2)+4*hb)
        #pragma unroll
        for (int i = 0; i < 2; ++i) {
            float xv[16];
            #pragma unroll
            for (int g = 0; g < 4; ++g) {
                const float4 v =
                    *(const float4*)(xsqg + row0 + 32 * i + 8 * g + 4 * hb);
                xv[4 * g + 0] = v.x; xv[4 * g + 1] = v.y;
                xv[4 * g + 2] = v.z; xv[4 * g + 3] = v.w;
            }
            #pragma unroll
            for (int j = 0; j < 2; ++j) {
                const float zz = j ? zs1 : zs0;
                const int col = wid * 64 + 32 * j + l32;
                #pragma unroll
                for (int r = 0; r < 16; ++r) {
                    const int xrow = 32 * i + (r & 3) + 8 * (r >> 2) + 4 * hb;
                    const float xpz = xv[r] + zz;
                    float d2 = fmaf(S[i][j][r], -2.0f, xpz);
                    d2 = fmaxf(d2, 1e-20f);
                    const float dist = d2 * __frsqrt_rn(d2);     // sqrt(d2)
                    const float e = __builtin_amdgcn_exp2f(
                        dist * -0.14426950408889634f);           // exp(-dist/10)
                    R2[xrow * LDP + col] =
                        (ushort)(__builtin_bit_cast(unsigned, e) >> 16);
                }
            }
        }
        __syncthreads();   // B2: sP ready

        // ---- PV: O += P[64x256].W[256x256]; A from sP (R2), B = wb ----
        frag8 pa[2][2];
        #pragma unroll
        for (int p = 0; p < 2; ++p)
            #pragma unroll
            for (int i = 0; i < 2; ++i)
                pa[p][i] = *(const frag8*)(R2 + pa0 + i * 32 * LDP + p * 16);
        #pragma unroll
        for (int zw = 0; zw < 16; ++zw) {
            const int s2 = zw & 1, ws = zw & 3;
            __builtin_amdgcn_s_setprio(1);
            Oa[0][0] = __builtin_amdgcn_mfma_f32_32x32x16_bf16(
                pa[s2][0], wb[ws][0], Oa[0][0], 0, 0, 0);
            Oa[0][1] = __builtin_amdgcn_mfma_f32_32x32x16_bf16(
                pa[s2][0], wb[ws][1], Oa[0][1], 0, 0, 0);
            Oa[1][0] = __builtin_amdgcn_mfma_f32_32x32x16_bf16(
                pa[s2][1], wb[ws][0], Oa[1][0], 0, 0, 0);
            Oa[1][1] = __builtin_amdgcn_mfma_f32_32x32x16_bf16(
                pa[s2][1], wb[ws][1], Oa[1][1], 0, 0, 0);
            __builtin_amdgcn_s_setprio(0);
            if (zw + 2 < 16) {
                #pragma unroll
                for (int i = 0; i < 2; ++i)
                    pa[s2][i] = *(const frag8*)(
                        R2 + pa0 + i * 32 * LDP + (zw + 2) * 16);
            }
            if (zw + 4 < 16) {
                wb[ws][0] = *(const frag8*)(Wf + wo0
                                            + (unsigned)(zw + 4) * 256u);
                wb[ws][1] = *(const frag8*)(Wf + wo0 + 262144u
                                            + (unsigned)(zw + 4) * 256u);
            }
        }
        __syncthreads();   // B3: sP reads done, R2 free

        // ---- tail: restage X h1 (8 gloads, OLDEST); then next-mt zb ----
        if (mt + 1 < MT) {
            #pragma unroll
            for (int q = 0; q < 8; ++q) {
                const int f = wid * 8 + q;        // 0..31
                const int kw = (f >> 1) + 16, i = f & 1;
                gload_lds16(Xf + xsrc_base + (unsigned)i * 16384u
                               + (unsigned)kw * 256u,
                            R2 + f * 512);
            }
            __builtin_amdgcn_sched_barrier(0);    // pin order: gloads first
            zo0 += 131072u; zo1 += 131072u;
            #pragma unroll
            for (int p = 0; p < 4; ++p) {
                zb[p][0] = *(const frag8*)(Zf + zo0 + (unsigned)p * 256u);
                zb[p][1] = *(const frag8*)(Zf + zo1 + (unsigned)p * 256u);
            }
        }
        zwg += 16u;
    }

    // ---- epilogue: combine MCH=4 chunks via fp32 atomics (XCD-local) ----
    #pragma unroll
    for (int i = 0; i < 2; ++i)
        #pragma unroll
        for (int jy = 0; jy < 2; ++jy) {
            const int yg = wid * 64 + 32 * jy + l32;
            #pragma unroll
            for (int r = 0; r < 16; ++r) {
                const int xg = row0 + 32 * i + (r & 3) + 8 * (r >> 2) + 4 * hb;
                atomicAdd(&O[(size_t)xg * Yd + yg], Oa[i][jy][r]);
            }
        }
}

// ---- fallback (fp32 VALU fused kernel) if workspace is too small ----
constexpr int FBM = 64, FBN = 64, FBK = 64;
constexpr int FMCH = 4, FMCHUNK = Mm / FMCH, FMSTEPS = FMCHUNK / FBN, FDSTEPS = Dd / FBK;
constexpr int FLDA = FBK + 1, FLDSS = FBN + 1;

__global__ __launch_bounds__(256, 3) void laplace_fused_v1(
    const float* __restrict__ X, const float* __restrict__ Z,
    const float* __restrict__ W, float* __restrict__ O)
{
    __shared__ float sX[FBM * FLDA];
    __shared__ float sZ[FBN * FLDA];
    __shared__ float sS[FBM * FLDSS];
    const int t = threadIdx.x, pr = t >> 4, pc = t & 15, sc4 = pc * 4;
    const int row0 = blockIdx.x * FBM, mbase = blockIdx.y * FMCHUNK;
    float o[4][4][4];
    #pragma unroll
    for (int i = 0; i < 4; ++i)
        for (int yb = 0; yb < 4; ++yb)
            for (int j = 0; j < 4; ++j) o[i][yb][j] = 0.0f;
    for (int ms = 0; ms < FMSTEPS; ++ms) {
        const int zrow0 = mbase + ms * FBN;
        float s[4][4];
        #pragma unroll
        for (int i = 0; i < 4; ++i)
            for (int j = 0; j < 4; ++j) s[i][j] = 0.0f;
        for (int kk = 0; kk < FDSTEPS; ++kk) {
            const int k0 = kk * FBK;
            __syncthreads();
            #pragma unroll
            for (int rep = 0; rep < 4; ++rep) {
                const int r = pr + rep * 16;
                const float4 xv = *reinterpret_cast<const float4*>(X + (size_t)(row0 + r) * Dd + k0 + sc4);
                const float4 zv = *reinterpret_cast<const float4*>(Z + (size_t)(zrow0 + r) * Dd + k0 + sc4);
                float* dx = sX + r * FLDA + sc4;
                dx[0] = xv.x; dx[1] = xv.y; dx[2] = xv.z; dx[3] = xv.w;
                float* dz = sZ + r * FLDA + sc4;
                dz[0] = zv.x; dz[1] = zv.y; dz[2] = zv.z; dz[3] = zv.w;
            }
            __syncthreads();
            #pragma unroll 4
            for (int k = 0; k < FBK; ++k) {
                float xr[4], zc[4];
                #pragma unroll
                for (int i = 0; i < 4; ++i) xr[i] = sX[(pr * 4 + i) * FLDA + k];
                #pragma unroll
                for (int j = 0; j < 4; ++j) zc[j] = sZ[(pc * 4 + j) * FLDA + k];
                #pragma unroll
                for (int i = 0; i < 4; ++i)
                    #pragma unroll
                    for (int j = 0; j < 4; ++j) {
                        const float d = xr[i] - zc[j];
                        s[i][j] = fmaf(d, d, s[i][j]);
                    }
            }
        }
        #pragma unroll
        for (int i = 0; i < 4; ++i)
            for (int j = 0; j < 4; ++j)
                sS[(pr * 4 + i) * FLDSS + sc4 + j] = __expf(-sqrtf(s[i][j]) * 0.1f);
        __syncthreads();
        #pragma unroll 2
        for (int c = 0; c < FBN; ++c) {
            float sv[4];
            #pragma unroll
            for (int i = 0; i < 4; ++i) sv[i] = sS[(pr * 4 + i) * FLDSS + c];
            const float* wrow = W + (size_t)(zrow0 + c) * Yd;
            #pragma unroll
            for (int yb = 0; yb < 4; ++yb) {
                const float4 wv = *reinterpret_cast<const float4*>(wrow + yb * 64 + sc4);
                #pragma unroll
                for (int i = 0; i < 4; ++i) {
                    o[i][yb][0] = fmaf(sv[i], wv.x, o[i][yb][0]);
                    o[i][yb][1] = fmaf(sv[i], wv.y, o[i][yb][1]);
                    o[i][yb][2] = fmaf(sv[i], wv.z, o[i][yb][2]);
                    o[i][yb][3] = fmaf(sv[i], wv.w, o[i][yb][3]);
                }
            }
        }
        __syncthreads();
    }
    #pragma unroll
    for (int i = 0; i < 4; ++i) {
        const size_t rbase = (size_t)(row0 + pr * 4 + i) * Yd;
        #pragma unroll
        for (int yb = 0; yb < 4; ++yb)
            for (int j = 0; j < 4; ++j)
                atomicAdd(O + rbase + yb * 64 + sc4 + j, o[i][yb][j]);
    }
}

extern "C" void kernel_launch(void* const* d_in, const int* in_sizes, int n_in,
                              void* d_out, int out_size, void* d_ws, size_t ws_size,
                              hipStream_t stream) {
    const float* X = (const float*)d_in[0];   // batch   [8192, 512]
    const float* Z = (const float*)d_in[1];   // centers [8192, 512]
    const float* W = (const float*)d_in[2];   // weight  [8192, 256]
    float* O = (float*)d_out;                 // pred    [8192, 256]

    hipMemsetAsync(d_out, 0, (size_t)out_size * sizeof(float), stream);

    if (ws_size < WS_NEED) {
        dim3 grid(Nn / FBM, FMCH);
        laplace_fused_v1<<<grid, dim3(256), 0, stream>>>(X, Z, W, O);
        return;
    }

    char* ws = (char*)d_ws;
    ushort* Xf  = (ushort*)(ws + OFF_XF);
    ushort* Zf  = (ushort*)(ws + OFF_ZF);
    ushort* Wf  = (ushort*)(ws + OFF_WF);
    float*  xsq = (float*)(ws + OFF_XSQ);
    float*  zsq = (float*)(ws + OFF_ZSQ);

    prep_v11<<<dim3(1024 + 256), dim3(256), 0, stream>>>(
        X, Z, W, Xf, Zf, Wf, xsq, zsq);

    laplace_v20<<<dim3(512), dim3(256), 0, stream>>>(
        Xf, Zf, Wf, xsq, zsq, O);
}